// Round 1
// baseline (752.662 us; speedup 1.0000x reference)
//
#include <hip/hip_runtime.h>
#include <math.h>

#define HW 65536
#define NC 10
#define NT 12
#define NSV 3
#define LAMBDA_F 0.05f
#define PI_F 3.14159265358979323846f

__device__ __forceinline__ float2 cadd(float2 a, float2 b){ return make_float2(a.x+b.x, a.y+b.y); }
__device__ __forceinline__ float2 csub(float2 a, float2 b){ return make_float2(a.x-b.x, a.y-b.y); }
__device__ __forceinline__ float2 cmul(float2 a, float2 b){ return make_float2(a.x*b.x-a.y*b.y, a.x*b.y+a.y*b.x); }
// conj(a)*b
__device__ __forceinline__ float2 cmulj(float2 a, float2 b){ return make_float2(a.x*b.x+a.y*b.y, a.x*b.y-a.y*b.x); }
__device__ __forceinline__ float2 cscale(float2 a, float s){ return make_float2(a.x*s, a.y*s); }

template<int SIGN>
__device__ __forceinline__ void radix4_nt(float2& a0, float2& a1, float2& a2, float2& a3){
  float2 t0=cadd(a0,a2), t1=csub(a0,a2), t2=cadd(a1,a3), t3=csub(a1,a3);
  float2 t3r;
  if constexpr (SIGN < 0) t3r = make_float2(t3.y, -t3.x); else t3r = make_float2(-t3.y, t3.x);
  a0=cadd(t0,t2); a1=cadd(t1,t3r); a2=csub(t0,t2); a3=csub(t1,t3r);
}

template<int SIGN>
__device__ __forceinline__ void radix4(float2& a0, float2& a1, float2& a2, float2& a3, int m, float inv4Ns){
  float ang = (float)SIGN * 2.0f * PI_F * (float)m * inv4Ns;
  float s, c;
  __sincosf(ang, &s, &c);
  float2 w1 = make_float2(c, s);
  float2 w2 = cmul(w1, w1);
  float2 w3 = cmul(w2, w1);
  a1 = cmul(a1, w1); a2 = cmul(a2, w2); a3 = cmul(a3, w3);
  radix4_nt<SIGN>(a0, a1, a2, a3);
}

// 256-pt Stockham radix-4 FFT, natural-in natural-out, unnormalized.
// 64 lanes (j) cooperate; input x0..x3 = data[j+64r]; output natural order at j+64r.
// b0,b1: LDS float2[256] scratch for this group. Leading barrier protects reuse.
template<int SIGN>
__device__ __forceinline__ void fft256(float2* b0, float2* b1, int j,
                                       float2& x0, float2& x1, float2& x2, float2& x3){
  __syncthreads();
  radix4_nt<SIGN>(x0,x1,x2,x3);
  b0[4*j]=x0; b0[4*j+1]=x1; b0[4*j+2]=x2; b0[4*j+3]=x3;
  __syncthreads();
  x0=b0[j]; x1=b0[j+64]; x2=b0[j+128]; x3=b0[j+192];
  radix4<SIGN>(x0,x1,x2,x3, j&3, 1.0f/16.0f);
  { int i=((j>>2)<<4)+(j&3); b1[i]=x0; b1[i+4]=x1; b1[i+8]=x2; b1[i+12]=x3; }
  __syncthreads();
  x0=b1[j]; x1=b1[j+64]; x2=b1[j+128]; x3=b1[j+192];
  radix4<SIGN>(x0,x1,x2,x3, j&15, 1.0f/64.0f);
  { int i=((j>>4)<<6)+(j&15); b0[i]=x0; b0[i+16]=x1; b0[i+32]=x2; b0[i+48]=x3; }
  __syncthreads();
  x0=b0[j]; x1=b0[j+64]; x2=b0[j+128]; x3=b0[j+192];
  radix4<SIGN>(x0,x1,x2,x3, j, 1.0f/256.0f);
}

// ---------- W precompute: W'(s,s')(kx,ky) = sum_t conj(L_ts)L_ts' * mask[t][ky+128][kx+128] /65536
// layout: W9[q][kx*256+ky], q in {d0,d1,d2,o01re,o01im,o02re,o02im,o12re,o12im}
__global__ __launch_bounds__(256) void k_precompute_W(const float* __restrict__ mask,
                                                      const float2* __restrict__ Lt,
                                                      float* __restrict__ W9,
                                                      float* __restrict__ scal){
  __shared__ float2 Ls[NT*NSV];
  int tid = threadIdx.x;
  if (tid < NT*NSV) Ls[tid] = Lt[tid];
  if (blockIdx.x == 0 && tid < 64) scal[tid] = 0.0f;
  __syncthreads();
  int idx = blockIdx.x*256 + tid;      // = kx*256 + ky
  int kx = idx >> 8, ky = idx & 255;
  int mx = (kx + 128) & 255, my = (ky + 128) & 255;
  float d0=0.f, d1=0.f, d2=0.f;
  float2 o01=make_float2(0,0), o02=make_float2(0,0), o12=make_float2(0,0);
  for (int t = 0; t < NT; t++){
    float m = mask[t*HW + my*256 + mx];
    float2 l0 = Ls[t*3+0], l1 = Ls[t*3+1], l2 = Ls[t*3+2];
    d0 += m*(l0.x*l0.x + l0.y*l0.y);
    d1 += m*(l1.x*l1.x + l1.y*l1.y);
    d2 += m*(l2.x*l2.x + l2.y*l2.y);
    o01 = cadd(o01, cscale(cmulj(l0,l1), m));
    o02 = cadd(o02, cscale(cmulj(l0,l2), m));
    o12 = cadd(o12, cscale(cmulj(l1,l2), m));
  }
  const float nrm = 1.0f/65536.0f;
  W9[idx]          = d0*nrm;  W9[idx+HW]   = d1*nrm;  W9[idx+2*HW] = d2*nrm;
  W9[idx+3*HW] = o01.x*nrm;   W9[idx+4*HW] = o01.y*nrm;
  W9[idx+5*HW] = o02.x*nrm;   W9[idx+6*HW] = o02.y*nrm;
  W9[idx+7*HW] = o12.x*nrm;   W9[idx+8*HW] = o12.y*nrm;
}

// ---------- g_{s,c} = D * sum_t conj(L_ts) y[t,c]  -> A[c*3+s]
__global__ __launch_bounds__(256) void k_compute_g(const float2* __restrict__ y,
                                                   const float2* __restrict__ Lt,
                                                   float2* __restrict__ A){
  __shared__ float2 Ls[NT*NSV];
  int tid = threadIdx.x;
  if (tid < NT*NSV) Ls[tid] = Lt[tid];
  __syncthreads();
  int idx = blockIdx.x*256 + tid;      // 0 .. 10*65536-1
  int c = idx >> 16, pix = idx & (HW-1);
  int xx = pix & 255, yy = pix >> 8;
  float sg = ((xx + yy) & 1) ? -1.0f : 1.0f;
  float2 a0=make_float2(0,0), a1=make_float2(0,0), a2=make_float2(0,0);
  for (int t = 0; t < NT; t++){
    float2 yv = y[((size_t)(t*NC + c))*HW + pix];
    a0 = cadd(a0, cmulj(Ls[t*3+0], yv));
    a1 = cadd(a1, cmulj(Ls[t*3+1], yv));
    a2 = cadd(a2, cmulj(Ls[t*3+2], yv));
  }
  A[((size_t)(c*3+0))*HW + pix] = cscale(a0, sg);
  A[((size_t)(c*3+1))*HW + pix] = cscale(a1, sg);
  A[((size_t)(c*3+2))*HW + pix] = cscale(a2, sg);
}

// ---------- row-direction FFT pass. grid (64 tiles, nplanes). 4 rows per WG.
// FUSED: input = sens[c] * p[s'] (plane pl = c*3+s'); else input = src[pl].
template<int SIGN, bool FUSED>
__global__ __launch_bounds__(256) void k_fft_rows(const float2* __restrict__ src,
                                                  float2* __restrict__ dst,
                                                  const float2* __restrict__ p,
                                                  const float2* __restrict__ sens){
  __shared__ float2 lds[2][4][256];
  int tid = threadIdx.x, g = tid >> 6, j = tid & 63;
  int pl = blockIdx.y;
  int row = blockIdx.x*4 + g;
  size_t base = (size_t)pl*HW + row*256;
  float2 x0, x1, x2, x3;
  if constexpr (FUSED) {
    int c = pl/3, sp = pl - 3*c;
    size_t pb = (size_t)sp*HW + row*256;
    size_t sb = (size_t)c*HW + row*256;
    x0 = cmul(sens[sb+j],     p[pb+j]);
    x1 = cmul(sens[sb+j+64],  p[pb+j+64]);
    x2 = cmul(sens[sb+j+128], p[pb+j+128]);
    x3 = cmul(sens[sb+j+192], p[pb+j+192]);
  } else {
    x0 = src[base+j]; x1 = src[base+j+64]; x2 = src[base+j+128]; x3 = src[base+j+192];
  }
  fft256<SIGN>(lds[0][g], lds[1][g], j, x0, x1, x2, x3);
  dst[base+j] = x0; dst[base+j+64] = x1; dst[base+j+128] = x2; dst[base+j+192] = x3;
}

// ---------- column-direction pass. Tile = 4 columns. Gathers via float4.
// DO_W: 3 s'-planes of coil c (blockIdx.y=c): ifft-cols (SIGN1=+1) -> 3x3 W-combine -> fft-cols(-1).
// else: single plane pl = blockIdx.y, one FFT with SIGN1.
template<int SIGN1, bool DO_W>
__global__ __launch_bounds__(256) void k_fft_cols(const float2* __restrict__ src,
                                                  float2* __restrict__ dst,
                                                  const float* __restrict__ W9){
  constexpr int NPL = DO_W ? 3 : 1;
  __shared__ float2 T[NPL][4][256];
  __shared__ float2 sc[2][4][256];
  int tid = threadIdx.x, g = tid >> 6, j = tid & 63;
  int colBase = blockIdx.x * 4;
  // gather
  for (int s = 0; s < NPL; s++){
    int pl = DO_W ? (blockIdx.y*3 + s) : blockIdx.y;
    const float4* s4 = (const float4*)(src + (size_t)pl*HW);
    for (int step = 0; step < 2; step++){
      int rrow = step*128 + (tid >> 1);
      int cp = tid & 1;
      float4 v = s4[(size_t)rrow*128 + (colBase >> 1) + cp];
      T[s][cp*2+0][rrow] = make_float2(v.x, v.y);
      T[s][cp*2+1][rrow] = make_float2(v.z, v.w);
    }
  }
  __syncthreads();
  // column FFT (direction SIGN1) per plane
  for (int s = 0; s < NPL; s++){
    float2 x0=T[s][g][j], x1=T[s][g][j+64], x2=T[s][g][j+128], x3=T[s][g][j+192];
    fft256<SIGN1>(sc[0][g], sc[1][g], j, x0, x1, x2, x3);
    T[s][g][j]=x0; T[s][g][j+64]=x1; T[s][g][j+128]=x2; T[s][g][j+192]=x3;
  }
  if constexpr (DO_W) {
    int kx = colBase + g;
    for (int rr = 0; rr < 4; rr++){
      int k = j + 64*rr;
      size_t wi = (size_t)kx*256 + k;
      float d0 = W9[wi], d1 = W9[wi+HW], d2 = W9[wi+2*HW];
      float2 o01 = make_float2(W9[wi+3*HW], W9[wi+4*HW]);
      float2 o02 = make_float2(W9[wi+5*HW], W9[wi+6*HW]);
      float2 o12 = make_float2(W9[wi+7*HW], W9[wi+8*HW]);
      float2 v0 = T[0][g][k], v1 = T[1][g][k], v2 = T[2][g][k];
      float2 u0 = cadd(cadd(cscale(v0,d0), cmul(o01,v1)), cmul(o02,v2));
      float2 u1 = cadd(cadd(cmulj(o01,v0), cscale(v1,d1)), cmul(o12,v2));
      float2 u2 = cadd(cadd(cmulj(o02,v0), cmulj(o12,v1)), cscale(v2,d2));
      T[0][g][k]=u0; T[1][g][k]=u1; T[2][g][k]=u2;
    }
    for (int s = 0; s < 3; s++){
      float2 x0=T[s][g][j], x1=T[s][g][j+64], x2=T[s][g][j+128], x3=T[s][g][j+192];
      fft256<-1>(sc[0][g], sc[1][g], j, x0, x1, x2, x3);
      T[s][g][j]=x0; T[s][g][j+64]=x1; T[s][g][j+128]=x2; T[s][g][j+192]=x3;
    }
  }
  __syncthreads();
  // scatter
  for (int s = 0; s < NPL; s++){
    int pl = DO_W ? (blockIdx.y*3 + s) : blockIdx.y;
    float4* d4 = (float4*)(dst + (size_t)pl*HW);
    for (int step = 0; step < 2; step++){
      int rrow = step*128 + (tid >> 1);
      int cp = tid & 1;
      float2 a = T[s][cp*2+0][rrow], b = T[s][cp*2+1][rrow];
      d4[(size_t)rrow*128 + (colBase >> 1) + cp] = make_float4(a.x, a.y, b.x, b.y);
    }
  }
}

// ---------- b = D * sum_c conj(S_c) * A[c*3+s] + lambda*mo ; p=r=b ; z=0 ; rs0 += |b|^2
__global__ __launch_bounds__(256) void k_compute_b(const float2* __restrict__ A,
                                                   const float2* __restrict__ sens,
                                                   const float2* __restrict__ mo,
                                                   float2* __restrict__ p,
                                                   float2* __restrict__ r,
                                                   float2* __restrict__ z,
                                                   float* __restrict__ scal){
  __shared__ float red[4];
  int idx = blockIdx.x*256 + threadIdx.x;   // 0..196607
  int s = idx >> 16, pix = idx & (HW-1);
  int xx = pix & 255, yy = pix >> 8;
  float sg = ((xx + yy) & 1) ? -1.0f : 1.0f;
  float2 accv = make_float2(0,0);
  for (int c = 0; c < NC; c++)
    accv = cadd(accv, cmulj(sens[(size_t)c*HW + pix], A[((size_t)(c*3+s))*HW + pix]));
  float2 b = cadd(cscale(accv, sg), cscale(mo[idx], LAMBDA_F));
  p[idx] = b; r[idx] = b; z[idx] = make_float2(0,0);
  float part = b.x*b.x + b.y*b.y;
  for (int off = 32; off; off >>= 1) part += __shfl_down(part, off);
  int j = threadIdx.x & 63, w = threadIdx.x >> 6;
  if (j == 0) red[w] = part;
  __syncthreads();
  if (threadIdx.x == 0) atomicAdd(&scal[0], red[0]+red[1]+red[2]+red[3]);
}

// ---------- final row FFT + conj(S) accumulate over c + lambda*p -> Ap; pAp partial
__global__ __launch_bounds__(256) void k_fft_rows_acc(const float2* __restrict__ Bp,
                                                      const float2* __restrict__ sens,
                                                      const float2* __restrict__ p,
                                                      float2* __restrict__ Ap,
                                                      float* __restrict__ scal, int iter){
  __shared__ float2 lds[2][4][256];
  __shared__ float2 acc[4][256];
  __shared__ float2 wred[4];
  int tid = threadIdx.x, g = tid >> 6, j = tid & 63;
  int row = blockIdx.x, s = blockIdx.y;
  acc[g][j]=make_float2(0,0); acc[g][j+64]=make_float2(0,0);
  acc[g][j+128]=make_float2(0,0); acc[g][j+192]=make_float2(0,0);
  for (int cc = 0; cc < 3; cc++){
    int c = cc*4 + g;
    bool act = (c < NC);
    float2 x0=make_float2(0,0), x1=x0, x2=x0, x3=x0;
    size_t base = ((size_t)(c*3+s))*HW + row*256;
    if (act){
      x0 = Bp[base+j]; x1 = Bp[base+j+64]; x2 = Bp[base+j+128]; x3 = Bp[base+j+192];
    }
    fft256<-1>(lds[0][g], lds[1][g], j, x0, x1, x2, x3);
    if (act){
      size_t sb = (size_t)c*HW + row*256;
      acc[g][j]     = cadd(acc[g][j],     cmulj(sens[sb+j],     x0));
      acc[g][j+64]  = cadd(acc[g][j+64],  cmulj(sens[sb+j+64],  x1));
      acc[g][j+128] = cadd(acc[g][j+128], cmulj(sens[sb+j+128], x2));
      acc[g][j+192] = cadd(acc[g][j+192], cmulj(sens[sb+j+192], x3));
    }
  }
  __syncthreads();
  int k = tid;
  size_t ob = (size_t)s*HW + row*256 + k;
  float2 a = cadd(cadd(acc[0][k], acc[1][k]), cadd(acc[2][k], acc[3][k]));
  float2 pv = p[ob];
  float2 ap = cadd(a, cscale(pv, LAMBDA_F));
  Ap[ob] = ap;
  float2 pap = cmulj(pv, ap);
  for (int off = 32; off; off >>= 1){
    pap.x += __shfl_down(pap.x, off);
    pap.y += __shfl_down(pap.y, off);
  }
  if (j == 0) wred[g] = pap;
  __syncthreads();
  if (tid == 0){
    float2 tot = cadd(cadd(wred[0], wred[1]), cadd(wred[2], wred[3]));
    atomicAdd(&scal[16 + 2*iter],     tot.x);
    atomicAdd(&scal[16 + 2*iter + 1], tot.y);
  }
}

// ---------- z += alpha p ; r -= alpha Ap ; rs[i+1] += |r|^2
__global__ __launch_bounds__(256) void k_update_zr(float2* __restrict__ z,
                                                   float2* __restrict__ r,
                                                   const float2* __restrict__ p,
                                                   const float2* __restrict__ Ap,
                                                   float* __restrict__ scal, int iter){
  __shared__ float red[4];
  int idx = blockIdx.x*256 + threadIdx.x;
  float rs = scal[iter];
  float2 pap = make_float2(scal[16+2*iter], scal[16+2*iter+1]);
  float den = pap.x*pap.x + pap.y*pap.y;
  float inv = rs / den;
  float2 alpha = make_float2(pap.x*inv, -pap.y*inv);
  float2 pv = p[idx], apv = Ap[idx];
  float2 zv = cadd(z[idx], cmul(alpha, pv));
  float2 rv = csub(r[idx], cmul(alpha, apv));
  z[idx] = zv; r[idx] = rv;
  float part = rv.x*rv.x + rv.y*rv.y;
  for (int off = 32; off; off >>= 1) part += __shfl_down(part, off);
  int j = threadIdx.x & 63, w = threadIdx.x >> 6;
  if (j == 0) red[w] = part;
  __syncthreads();
  if (threadIdx.x == 0) atomicAdd(&scal[iter+1], red[0]+red[1]+red[2]+red[3]);
}

// ---------- p = r + beta p
__global__ __launch_bounds__(256) void k_update_p(float2* __restrict__ p,
                                                  const float2* __restrict__ r,
                                                  const float* __restrict__ scal, int iter){
  int idx = blockIdx.x*256 + threadIdx.x;
  float beta = scal[iter+1] / scal[iter];
  p[idx] = cadd(r[idx], cscale(p[idx], beta));
}

extern "C" void kernel_launch(void* const* d_in, const int* in_sizes, int n_in,
                              void* d_out, int out_size, void* d_ws, size_t ws_size,
                              hipStream_t stream){
  const float2* y    = (const float2*)d_in[0];
  const float2* mo   = (const float2*)d_in[1];
  const float2* sens = (const float2*)d_in[2];
  const float2* Lt   = (const float2*)d_in[3];
  const float*  mask = (const float*)d_in[4];

  float* w = (float*)d_ws;
  float*  scal = w;                                  // 64 floats
  float*  W9   = w + 64;                             // 9*65536 floats
  float2* A    = (float2*)(w + 64 + 9*HW);           // 30 planes
  float2* Bb   = A + (size_t)30*HW;                  // 30 planes
  float2* p    = Bb + (size_t)30*HW;                 // 3 planes
  float2* r    = p + (size_t)3*HW;
  float2* Ap   = r + (size_t)3*HW;
  float2* z    = (float2*)d_out;

  // setup
  k_precompute_W<<<256, 256, 0, stream>>>(mask, Lt, W9, scal);
  k_compute_g<<<2560, 256, 0, stream>>>(y, Lt, A);
  k_fft_rows<-1, false><<<dim3(64, 30), 256, 0, stream>>>(A, Bb, nullptr, nullptr);
  k_fft_cols<-1, false><<<dim3(64, 30), 256, 0, stream>>>(Bb, A, nullptr);
  k_compute_b<<<768, 256, 0, stream>>>(A, sens, mo, p, r, z, scal);

  // CG iterations
  for (int it = 0; it < 10; it++){
    k_fft_rows<1, true><<<dim3(64, 30), 256, 0, stream>>>(nullptr, A, p, sens);
    k_fft_cols<1, true><<<dim3(64, 10), 256, 0, stream>>>(A, Bb, W9);
    k_fft_rows_acc<<<dim3(256, 3), 256, 0, stream>>>(Bb, sens, p, Ap, scal, it);
    k_update_zr<<<768, 256, 0, stream>>>(z, r, p, Ap, scal, it);
    k_update_p<<<768, 256, 0, stream>>>(p, r, scal, it);
  }
}

// Round 2
// 723.461 us; speedup vs baseline: 1.0404x; 1.0404x over previous
//
#include <hip/hip_runtime.h>
#include <math.h>

#define HW 65536
#define NC 10
#define NT 12
#define NSV 3
#define LAMBDA_F 0.05f
#define PI_F 3.14159265358979323846f
// XOR-swizzle for LDS scratch: uniform 4 lanes/bank-pair on both the stride-4
// scatter writes and the stride-64 reads (b64 conflict-free minimum).
#define SWZ(i) ((i) ^ ((i) >> 4))

__device__ __forceinline__ float2 cadd(float2 a, float2 b){ return make_float2(a.x+b.x, a.y+b.y); }
__device__ __forceinline__ float2 csub(float2 a, float2 b){ return make_float2(a.x-b.x, a.y-b.y); }
__device__ __forceinline__ float2 cmul(float2 a, float2 b){ return make_float2(a.x*b.x-a.y*b.y, a.x*b.y+a.y*b.x); }
// conj(a)*b
__device__ __forceinline__ float2 cmulj(float2 a, float2 b){ return make_float2(a.x*b.x+a.y*b.y, a.x*b.y-a.y*b.x); }
__device__ __forceinline__ float2 cscale(float2 a, float s){ return make_float2(a.x*s, a.y*s); }

template<int SIGN>
__device__ __forceinline__ void radix4_nt(float2& a0, float2& a1, float2& a2, float2& a3){
  float2 t0=cadd(a0,a2), t1=csub(a0,a2), t2=cadd(a1,a3), t3=csub(a1,a3);
  float2 t3r;
  if constexpr (SIGN < 0) t3r = make_float2(t3.y, -t3.x); else t3r = make_float2(-t3.y, t3.x);
  a0=cadd(t0,t2); a1=cadd(t1,t3r); a2=csub(t0,t2); a3=csub(t1,t3r);
}

// twiddle from LUT: tw[e] = exp(-2*pi*i*e/256); conj for SIGN=+1
template<int SIGN>
__device__ __forceinline__ float2 twl(const float2* tw, int e){
  float2 w = tw[e];
  if constexpr (SIGN > 0) w.y = -w.y;
  return w;
}

template<int SIGN>
__device__ __forceinline__ void radix4_tw(float2& a0, float2& a1, float2& a2, float2& a3,
                                          const float2* tw, int e){
  float2 w1 = twl<SIGN>(tw, e);
  float2 w2 = cmul(w1, w1);
  float2 w3 = cmul(w1, w2);
  a1 = cmul(a1, w1); a2 = cmul(a2, w2); a3 = cmul(a3, w3);
  radix4_nt<SIGN>(a0, a1, a2, a3);
}

// 256-pt Stockham radix-4 FFT, natural-in natural-out, unnormalized.
// BARRIER-FREE: b0/b1 scratch must be private to the calling wave (64 lanes).
// Per-wave LDS ops execute in order; sched_barrier(0) fences stop compiler
// motion across the may-alias write->read phase boundaries.
template<int SIGN>
__device__ __forceinline__ void fft256(float2* b0, float2* b1, const float2* tw, int j,
                                       float2& x0, float2& x1, float2& x2, float2& x3){
  radix4_nt<SIGN>(x0,x1,x2,x3);
  b0[SWZ(4*j)]=x0; b0[SWZ(4*j+1)]=x1; b0[SWZ(4*j+2)]=x2; b0[SWZ(4*j+3)]=x3;
  __builtin_amdgcn_sched_barrier(0);
  x0=b0[SWZ(j)]; x1=b0[SWZ(j+64)]; x2=b0[SWZ(j+128)]; x3=b0[SWZ(j+192)];
  __builtin_amdgcn_sched_barrier(0);
  radix4_tw<SIGN>(x0,x1,x2,x3, tw, (j&3)<<4);
  { int i=((j>>2)<<4)+(j&3); b1[SWZ(i)]=x0; b1[SWZ(i+4)]=x1; b1[SWZ(i+8)]=x2; b1[SWZ(i+12)]=x3; }
  __builtin_amdgcn_sched_barrier(0);
  x0=b1[SWZ(j)]; x1=b1[SWZ(j+64)]; x2=b1[SWZ(j+128)]; x3=b1[SWZ(j+192)];
  __builtin_amdgcn_sched_barrier(0);
  radix4_tw<SIGN>(x0,x1,x2,x3, tw, (j&15)<<2);
  { int i=((j>>4)<<6)+(j&15); b0[SWZ(i)]=x0; b0[SWZ(i+16)]=x1; b0[SWZ(i+32)]=x2; b0[SWZ(i+48)]=x3; }
  __builtin_amdgcn_sched_barrier(0);
  x0=b0[SWZ(j)]; x1=b0[SWZ(j+64)]; x2=b0[SWZ(j+128)]; x3=b0[SWZ(j+192)];
  __builtin_amdgcn_sched_barrier(0);
  radix4_tw<SIGN>(x0,x1,x2,x3, tw, j);
}

__device__ __forceinline__ void tw_init(float2* tw, int tid){
  float s, c;
  __sincosf(-2.0f*PI_F*(float)tid*(1.0f/256.0f), &s, &c);
  tw[tid] = make_float2(c, s);
}

// ---------- W precompute: W'(s,s')(kx,ky) = sum_t conj(L_ts)L_ts' * mask[t][ky+128][kx+128]/65536
__global__ __launch_bounds__(256) void k_precompute_W(const float* __restrict__ mask,
                                                      const float2* __restrict__ Lt,
                                                      float* __restrict__ W9,
                                                      float* __restrict__ scal){
  __shared__ float2 Ls[NT*NSV];
  int tid = threadIdx.x;
  if (tid < NT*NSV) Ls[tid] = Lt[tid];
  if (blockIdx.x == 0 && tid < 64) scal[tid] = 0.0f;
  __syncthreads();
  int idx = blockIdx.x*256 + tid;      // = kx*256 + ky
  int kx = idx >> 8, ky = idx & 255;
  int mx = (kx + 128) & 255, my = (ky + 128) & 255;
  float d0=0.f, d1=0.f, d2=0.f;
  float2 o01=make_float2(0,0), o02=make_float2(0,0), o12=make_float2(0,0);
  for (int t = 0; t < NT; t++){
    float m = mask[t*HW + my*256 + mx];
    float2 l0 = Ls[t*3+0], l1 = Ls[t*3+1], l2 = Ls[t*3+2];
    d0 += m*(l0.x*l0.x + l0.y*l0.y);
    d1 += m*(l1.x*l1.x + l1.y*l1.y);
    d2 += m*(l2.x*l2.x + l2.y*l2.y);
    o01 = cadd(o01, cscale(cmulj(l0,l1), m));
    o02 = cadd(o02, cscale(cmulj(l0,l2), m));
    o12 = cadd(o12, cscale(cmulj(l1,l2), m));
  }
  const float nrm = 1.0f/65536.0f;
  W9[idx]          = d0*nrm;  W9[idx+HW]   = d1*nrm;  W9[idx+2*HW] = d2*nrm;
  W9[idx+3*HW] = o01.x*nrm;   W9[idx+4*HW] = o01.y*nrm;
  W9[idx+5*HW] = o02.x*nrm;   W9[idx+6*HW] = o02.y*nrm;
  W9[idx+7*HW] = o12.x*nrm;   W9[idx+8*HW] = o12.y*nrm;
}

// ---------- g_{s,c} = D * sum_t conj(L_ts) y[t,c]  -> A[c*3+s]
__global__ __launch_bounds__(256) void k_compute_g(const float2* __restrict__ y,
                                                   const float2* __restrict__ Lt,
                                                   float2* __restrict__ A){
  __shared__ float2 Ls[NT*NSV];
  int tid = threadIdx.x;
  if (tid < NT*NSV) Ls[tid] = Lt[tid];
  __syncthreads();
  int idx = blockIdx.x*256 + tid;
  int c = idx >> 16, pix = idx & (HW-1);
  int xx = pix & 255, yy = pix >> 8;
  float sg = ((xx + yy) & 1) ? -1.0f : 1.0f;
  float2 a0=make_float2(0,0), a1=make_float2(0,0), a2=make_float2(0,0);
  for (int t = 0; t < NT; t++){
    float2 yv = y[((size_t)(t*NC + c))*HW + pix];
    a0 = cadd(a0, cmulj(Ls[t*3+0], yv));
    a1 = cadd(a1, cmulj(Ls[t*3+1], yv));
    a2 = cadd(a2, cmulj(Ls[t*3+2], yv));
  }
  A[((size_t)(c*3+0))*HW + pix] = cscale(a0, sg);
  A[((size_t)(c*3+1))*HW + pix] = cscale(a1, sg);
  A[((size_t)(c*3+2))*HW + pix] = cscale(a2, sg);
}

// ---------- setup row FFT (SIGN=-1), 30 planes
__global__ __launch_bounds__(256) void k_fft_rows_plain(const float2* __restrict__ src,
                                                        float2* __restrict__ dst){
  __shared__ float2 lds0[4][256], lds1[4][256];
  __shared__ float2 tw[256];
  int tid = threadIdx.x, g = tid >> 6, j = tid & 63;
  tw_init(tw, tid);
  __syncthreads();
  int pl = blockIdx.y, row = blockIdx.x*4 + g;
  size_t base = (size_t)pl*HW + row*256;
  float2 x0=src[base+j], x1=src[base+j+64], x2=src[base+j+128], x3=src[base+j+192];
  fft256<-1>(lds0[g], lds1[g], tw, j, x0,x1,x2,x3);
  dst[base+j]=x0; dst[base+j+64]=x1; dst[base+j+128]=x2; dst[base+j+192]=x3;
}

// ---------- CG-op first row pass (SIGN=+1), fused: p-update + sens multiply.
// iter==0: pv = pprev (= b). iter>0: pv = r + beta*pprev, beta=rs[i]/rs[i-1];
// c==0 blocks materialize pv into pout for the later kernels.
__global__ __launch_bounds__(256) void k_fft_rows_op(const float2* __restrict__ rbuf,
                                                     const float2* __restrict__ pprev,
                                                     float2* __restrict__ pout,
                                                     const float2* __restrict__ sens,
                                                     float2* __restrict__ dst,
                                                     const float* __restrict__ scal, int iter){
  __shared__ float2 lds0[4][256], lds1[4][256];
  __shared__ float2 tw[256];
  int tid = threadIdx.x, g = tid >> 6, j = tid & 63;
  tw_init(tw, tid);
  __syncthreads();
  int pl = blockIdx.y; int c = pl/3, sp = pl - 3*c;
  int row = blockIdx.x*4 + g;
  size_t pb = (size_t)sp*HW + row*256;
  size_t sb = (size_t)c*HW + row*256;
  float2 pv0, pv1, pv2, pv3;
  if (iter == 0){
    pv0 = pprev[pb+j]; pv1 = pprev[pb+j+64]; pv2 = pprev[pb+j+128]; pv3 = pprev[pb+j+192];
  } else {
    float beta = scal[iter] / scal[iter-1];
    pv0 = cadd(rbuf[pb+j],     cscale(pprev[pb+j],     beta));
    pv1 = cadd(rbuf[pb+j+64],  cscale(pprev[pb+j+64],  beta));
    pv2 = cadd(rbuf[pb+j+128], cscale(pprev[pb+j+128], beta));
    pv3 = cadd(rbuf[pb+j+192], cscale(pprev[pb+j+192], beta));
    if (c == 0){
      pout[pb+j] = pv0; pout[pb+j+64] = pv1; pout[pb+j+128] = pv2; pout[pb+j+192] = pv3;
    }
  }
  float2 x0 = cmul(sens[sb+j],     pv0);
  float2 x1 = cmul(sens[sb+j+64],  pv1);
  float2 x2 = cmul(sens[sb+j+128], pv2);
  float2 x3 = cmul(sens[sb+j+192], pv3);
  fft256<1>(lds0[g], lds1[g], tw, j, x0,x1,x2,x3);
  dst[sb*0 + (size_t)pl*HW + row*256 + j] = x0;
  dst[(size_t)pl*HW + row*256 + j+64]  = x1;
  dst[(size_t)pl*HW + row*256 + j+128] = x2;
  dst[(size_t)pl*HW + row*256 + j+192] = x3;
}

// ---------- column pass. Tile = 4 columns. b0 scratch aliases the T row.
template<int SIGN1, bool DO_W>
__global__ __launch_bounds__(256) void k_fft_cols(const float2* __restrict__ src,
                                                  float2* __restrict__ dst,
                                                  const float* __restrict__ W9){
  constexpr int NPL = DO_W ? 3 : 1;
  __shared__ float2 T[NPL][4][256];
  __shared__ float2 sc[4][256];
  __shared__ float2 tw[256];
  int tid = threadIdx.x, g = tid >> 6, j = tid & 63;
  tw_init(tw, tid);
  int colBase = blockIdx.x * 4;
  for (int s = 0; s < NPL; s++){
    int pl = DO_W ? (blockIdx.y*3 + s) : blockIdx.y;
    const float4* s4 = (const float4*)(src + (size_t)pl*HW);
    for (int step = 0; step < 2; step++){
      int rrow = step*128 + (tid >> 1);
      int cp = tid & 1;
      float4 v = s4[(size_t)rrow*128 + (colBase >> 1) + cp];
      T[s][cp*2+0][rrow] = make_float2(v.x, v.y);
      T[s][cp*2+1][rrow] = make_float2(v.z, v.w);
    }
  }
  __syncthreads();
  for (int s = 0; s < NPL; s++){
    float2 x0=T[s][g][j], x1=T[s][g][j+64], x2=T[s][g][j+128], x3=T[s][g][j+192];
    fft256<SIGN1>(T[s][g], sc[g], tw, j, x0,x1,x2,x3);
    T[s][g][j]=x0; T[s][g][j+64]=x1; T[s][g][j+128]=x2; T[s][g][j+192]=x3;
  }
  if constexpr (DO_W) {
    int kx = colBase + g;
    for (int rr = 0; rr < 4; rr++){
      int k = j + 64*rr;
      size_t wi = (size_t)kx*256 + k;
      float d0 = W9[wi], d1 = W9[wi+HW], d2 = W9[wi+2*HW];
      float2 o01 = make_float2(W9[wi+3*HW], W9[wi+4*HW]);
      float2 o02 = make_float2(W9[wi+5*HW], W9[wi+6*HW]);
      float2 o12 = make_float2(W9[wi+7*HW], W9[wi+8*HW]);
      float2 v0 = T[0][g][k], v1 = T[1][g][k], v2 = T[2][g][k];
      float2 u0 = cadd(cadd(cscale(v0,d0), cmul(o01,v1)), cmul(o02,v2));
      float2 u1 = cadd(cadd(cmulj(o01,v0), cscale(v1,d1)), cmul(o12,v2));
      float2 u2 = cadd(cadd(cmulj(o02,v0), cmulj(o12,v1)), cscale(v2,d2));
      T[0][g][k]=u0; T[1][g][k]=u1; T[2][g][k]=u2;
    }
    for (int s = 0; s < 3; s++){
      float2 x0=T[s][g][j], x1=T[s][g][j+64], x2=T[s][g][j+128], x3=T[s][g][j+192];
      fft256<-1>(T[s][g], sc[g], tw, j, x0,x1,x2,x3);
      T[s][g][j]=x0; T[s][g][j+64]=x1; T[s][g][j+128]=x2; T[s][g][j+192]=x3;
    }
  }
  __syncthreads();
  for (int s = 0; s < NPL; s++){
    int pl = DO_W ? (blockIdx.y*3 + s) : blockIdx.y;
    float4* d4 = (float4*)(dst + (size_t)pl*HW);
    for (int step = 0; step < 2; step++){
      int rrow = step*128 + (tid >> 1);
      int cp = tid & 1;
      float2 a = T[s][cp*2+0][rrow], b = T[s][cp*2+1][rrow];
      d4[(size_t)rrow*128 + (colBase >> 1) + cp] = make_float4(a.x, a.y, b.x, b.y);
    }
  }
}

// ---------- b = D * sum_c conj(S_c) * A[c*3+s] + lambda*mo ; p=r=b ; z=0 ; rs0 += |b|^2
__global__ __launch_bounds__(256) void k_compute_b(const float2* __restrict__ A,
                                                   const float2* __restrict__ sens,
                                                   const float2* __restrict__ mo,
                                                   float2* __restrict__ p,
                                                   float2* __restrict__ r,
                                                   float2* __restrict__ z,
                                                   float* __restrict__ scal){
  __shared__ float red[4];
  int idx = blockIdx.x*256 + threadIdx.x;
  int s = idx >> 16, pix = idx & (HW-1);
  int xx = pix & 255, yy = pix >> 8;
  float sg = ((xx + yy) & 1) ? -1.0f : 1.0f;
  float2 accv = make_float2(0,0);
  for (int c = 0; c < NC; c++)
    accv = cadd(accv, cmulj(sens[(size_t)c*HW + pix], A[((size_t)(c*3+s))*HW + pix]));
  float2 b = cadd(cscale(accv, sg), cscale(mo[idx], LAMBDA_F));
  p[idx] = b; r[idx] = b; z[idx] = make_float2(0,0);
  float part = b.x*b.x + b.y*b.y;
  for (int off = 32; off; off >>= 1) part += __shfl_down(part, off);
  int j = threadIdx.x & 63, w = threadIdx.x >> 6;
  if (j == 0) red[w] = part;
  __syncthreads();
  if (threadIdx.x == 0) atomicAdd(&scal[0], red[0]+red[1]+red[2]+red[3]);
}

// ---------- final row FFT + conj(S) accumulate over c + lambda*p -> Ap; pAp partial
__global__ __launch_bounds__(256) void k_fft_rows_acc(const float2* __restrict__ Bp,
                                                      const float2* __restrict__ sens,
                                                      const float2* __restrict__ p,
                                                      float2* __restrict__ Ap,
                                                      float* __restrict__ scal, int iter){
  __shared__ float2 lds0[4][256], lds1[4][256];
  __shared__ float2 acc[4][256];
  __shared__ float2 tw[256];
  __shared__ float2 wred[4];
  int tid = threadIdx.x, g = tid >> 6, j = tid & 63;
  tw_init(tw, tid);
  __syncthreads();
  int row = blockIdx.x, s = blockIdx.y;
  acc[g][j]=make_float2(0,0); acc[g][j+64]=make_float2(0,0);
  acc[g][j+128]=make_float2(0,0); acc[g][j+192]=make_float2(0,0);
  for (int cc = 0; cc < 3; cc++){
    int c = cc*4 + g;
    if (c < NC){
      size_t base = ((size_t)(c*3+s))*HW + row*256;
      float2 x0 = Bp[base+j], x1 = Bp[base+j+64], x2 = Bp[base+j+128], x3 = Bp[base+j+192];
      fft256<-1>(lds0[g], lds1[g], tw, j, x0,x1,x2,x3);
      size_t sb = (size_t)c*HW + row*256;
      acc[g][j]     = cadd(acc[g][j],     cmulj(sens[sb+j],     x0));
      acc[g][j+64]  = cadd(acc[g][j+64],  cmulj(sens[sb+j+64],  x1));
      acc[g][j+128] = cadd(acc[g][j+128], cmulj(sens[sb+j+128], x2));
      acc[g][j+192] = cadd(acc[g][j+192], cmulj(sens[sb+j+192], x3));
    }
  }
  __syncthreads();
  int k = tid;
  size_t ob = (size_t)s*HW + row*256 + k;
  float2 a = cadd(cadd(acc[0][k], acc[1][k]), cadd(acc[2][k], acc[3][k]));
  float2 pv = p[ob];
  float2 ap = cadd(a, cscale(pv, LAMBDA_F));
  Ap[ob] = ap;
  float2 pap = cmulj(pv, ap);
  for (int off = 32; off; off >>= 1){
    pap.x += __shfl_down(pap.x, off);
    pap.y += __shfl_down(pap.y, off);
  }
  if (j == 0) wred[g] = pap;
  __syncthreads();
  if (tid == 0){
    float2 tot = cadd(cadd(wred[0], wred[1]), cadd(wred[2], wred[3]));
    atomicAdd(&scal[16 + 2*iter],     tot.x);
    atomicAdd(&scal[16 + 2*iter + 1], tot.y);
  }
}

// ---------- z += alpha p ; r -= alpha Ap ; rs[i+1] += |r|^2
__global__ __launch_bounds__(256) void k_update_zr(float2* __restrict__ z,
                                                   float2* __restrict__ r,
                                                   const float2* __restrict__ p,
                                                   const float2* __restrict__ Ap,
                                                   float* __restrict__ scal, int iter){
  __shared__ float red[4];
  int idx = blockIdx.x*256 + threadIdx.x;
  float rs = scal[iter];
  float2 pap = make_float2(scal[16+2*iter], scal[16+2*iter+1]);
  float den = pap.x*pap.x + pap.y*pap.y;
  float inv = rs / den;
  float2 alpha = make_float2(pap.x*inv, -pap.y*inv);
  float2 pv = p[idx], apv = Ap[idx];
  float2 zv = cadd(z[idx], cmul(alpha, pv));
  float2 rv = csub(r[idx], cmul(alpha, apv));
  z[idx] = zv; r[idx] = rv;
  float part = rv.x*rv.x + rv.y*rv.y;
  for (int off = 32; off; off >>= 1) part += __shfl_down(part, off);
  int j = threadIdx.x & 63, w = threadIdx.x >> 6;
  if (j == 0) red[w] = part;
  __syncthreads();
  if (threadIdx.x == 0) atomicAdd(&scal[iter+1], red[0]+red[1]+red[2]+red[3]);
}

extern "C" void kernel_launch(void* const* d_in, const int* in_sizes, int n_in,
                              void* d_out, int out_size, void* d_ws, size_t ws_size,
                              hipStream_t stream){
  const float2* y    = (const float2*)d_in[0];
  const float2* mo   = (const float2*)d_in[1];
  const float2* sens = (const float2*)d_in[2];
  const float2* Lt   = (const float2*)d_in[3];
  const float*  mask = (const float*)d_in[4];

  float* w = (float*)d_ws;
  float*  scal = w;                                  // 64 floats
  float*  W9   = w + 64;                             // 9*65536 floats
  float2* A    = (float2*)(w + 64 + 9*HW);           // 30 planes
  float2* Bb   = A + (size_t)30*HW;                  // 30 planes
  float2* p0   = Bb + (size_t)30*HW;                 // 3 planes
  float2* p1   = p0 + (size_t)3*HW;                  // 3 planes
  float2* r    = p1 + (size_t)3*HW;
  float2* Ap   = r + (size_t)3*HW;
  float2* z    = (float2*)d_out;

  // setup
  k_precompute_W<<<256, 256, 0, stream>>>(mask, Lt, W9, scal);
  k_compute_g<<<2560, 256, 0, stream>>>(y, Lt, A);
  k_fft_rows_plain<<<dim3(64, 30), 256, 0, stream>>>(A, Bb);
  k_fft_cols<-1, false><<<dim3(64, 30), 256, 0, stream>>>(Bb, A, nullptr);
  k_compute_b<<<768, 256, 0, stream>>>(A, sens, mo, p0, r, z, scal);

  // CG iterations (p-update folded into k_fft_rows_op)
  for (int it = 0; it < 10; it++){
    float2* pcur  = (it & 1) ? p1 : p0;
    float2* pprev = (it == 0) ? p0 : ((it & 1) ? p0 : p1);
    k_fft_rows_op<<<dim3(64, 30), 256, 0, stream>>>(r, pprev, pcur, sens, A, scal, it);
    k_fft_cols<1, true><<<dim3(64, 10), 256, 0, stream>>>(A, Bb, W9);
    k_fft_rows_acc<<<dim3(256, 3), 256, 0, stream>>>(Bb, sens, pcur, Ap, scal, it);
    k_update_zr<<<768, 256, 0, stream>>>(z, r, pcur, Ap, scal, it);
  }
}